// Round 1
// baseline (45.790 us; speedup 1.0000x reference)
//
#include <hip/hip_runtime.h>

// y[b,n] = x[b,n] * (window[n%512] + window[n%512 + 512])
//
// Derivation: reference is WOLA segment->unsegment with sqrt'd windows.
// y = x * sum_k wmat[k, n-k*hop]^2. wmat^2 undoes the sqrt, giving the base
// windows back. With S=1024, hop=512 each sample is covered by <=2 frames;
// the edge-corrected pre/post windows (pre[s]=w[s]+w[s+512] for s<512,
// post[s]=w[s]+w[s-512] for s>=512) exactly compensate the missing neighbor
// frame at both ends, so the summed gain is uniformly periodic:
//   g[r] = window[r] + window[r+512],  r = n mod 512.
// => pure elementwise multiply, memory-bound (268 MB traffic, ~43us roofline).

typedef float float4v __attribute__((ext_vector_type(4)));

__global__ __launch_bounds__(256) void Segmenter_23596550324744_kernel(
    const float* __restrict__ x,
    const float* __restrict__ window,
    float* __restrict__ y,
    long long n4_total) {
    const long long tid = (long long)blockIdx.x * blockDim.x + threadIdx.x;
    const long long stride = (long long)gridDim.x * blockDim.x;  // multiple of 128 by launch config

    // Position within the 512-float period, in float4 units. Because the
    // grid-stride (in float4s) is a multiple of 128, this is invariant
    // across the loop -> load the 4 gain values once into registers.
    const int r4 = (int)(tid & 127);
    const int r = r4 * 4;
    float4v g;
    g.x = window[r + 0] + window[r + 512];
    g.y = window[r + 1] + window[r + 513];
    g.z = window[r + 2] + window[r + 514];
    g.w = window[r + 3] + window[r + 515];

    const float4v* __restrict__ x4 = (const float4v*)x;
    float4v* __restrict__ y4 = (float4v*)y;
    for (long long i = tid; i < n4_total; i += stride) {
        y4[i] = x4[i] * g;
    }
}

extern "C" void kernel_launch(void* const* d_in, const int* in_sizes, int n_in,
                              void* d_out, int out_size, void* d_ws, size_t ws_size,
                              hipStream_t stream) {
    const float* x = (const float*)d_in[0];
    const float* window = (const float*)d_in[1];
    float* y = (float*)d_out;

    const long long n_total = (long long)in_sizes[0];  // 16 * 2097152 = 2^25
    const long long n4_total = n_total / 4;            // 2^23

    // 2048 blocks x 256 threads = 2^19 threads: stride in float4 units is a
    // multiple of 128 (the 512-float period / 4), keeping each thread's
    // gain registers loop-invariant. 16 float4 iterations per thread.
    const int block = 256;
    const int grid = 2048;
    Segmenter_23596550324744_kernel<<<grid, block, 0, stream>>>(x, window, y, n4_total);
}